// Round 19
// baseline (116.565 us; speedup 1.0000x reference)
//
#include <hip/hip_runtime.h>

// Truncated signature, depth=3, C=8, B=512, L=8192.
// Kernel 1 (R17 pipeline + hybrid lo-DS / hi-readlane broadcast):
//   one wave per (sample,chunk); lane (a,b)=(lane>>3,lane&7) owns S2[a][b],
//   S3[a][b][0..7]. Direct: S3[k] += cf*dx2[k][u], cf=S2+S1*db/2+da*db/6.
//   Broadcast operand dx2[k][u] split across pipes (DS was the wall at 2.5
//   instr/step; this gets it to ~1.66):
//     k=0..3: uniform ds_read_b128 from LO-ONLY A array [t'][4],
//             t'=t^((t>>3)&3) XOR swizzle (writes spread across banks).
//     k=4..7: v_readlane from staging regs e0t/e1t (compile-time lane+comp).
//   Bc [c][t] stride 68 -> per-lane da/db b128 reads (av/bv).
//   4-step blocks; block j+1's 6 b128 prefetched into named A/B register sets
//   while block j computes. launch_bounds(256,3): no spills (R12's failure).
// Kernel 2: per-sample in-order Chen combine of the G chunk signatures.

constexpr int B_ = 512;
constexpr int C_ = 8;
constexpr int L_ = 8192;
constexpr int NINC = L_ - 1;      // 8191 increments
constexpr int SIGDIM = 584;       // 8 + 64 + 512
constexpr int TILE = 64;          // steps per LDS tile
constexpr int BSTR = 68;          // Bc row stride (floats)
constexpr int AWSZ = 256;         // A lo-only: 64 slots x 4 floats
constexpr int BWSZ = C_ * BSTR;   // 544

__host__ __device__ constexpr int SW(int t) { return t ^ ((t >> 3) & 3); }

static __device__ __forceinline__ float rl(float v, int l) {
  return __int_as_float(__builtin_amdgcn_readlane(__float_as_int(v), l));
}

// load block J's operands into register set SET (compile-time offsets)
#define LDP(SET, J)                                           \
  do {                                                        \
    SET##p0 = *(const float4*)(as_ + SW((J) * 4 + 0) * 4);    \
    SET##p1 = *(const float4*)(as_ + SW((J) * 4 + 1) * 4);    \
    SET##p2 = *(const float4*)(as_ + SW((J) * 4 + 2) * 4);    \
    SET##p3 = *(const float4*)(as_ + SW((J) * 4 + 3) * 4);    \
    SET##av = *(const float4*)(pa + (J) * 4);                 \
    SET##bv = *(const float4*)(pb + (J) * 4);                 \
  } while (0)

// one step; EX = staging-reg component for this step; SI = source quad 0..7
#define STEP_H(DA, DB, PLO, EX, SI)                           \
  do {                                                        \
    const float w_ = __builtin_fmaf((DA), (2.f / 3.f), s1a);  \
    const float z_ = __builtin_fmaf((DA), (4.f / 3.f), s1a);  \
    const float cf = __builtin_fmaf((DB), w_, S2);            \
    S2  = __builtin_fmaf((DB), z_, cf);                       \
    s1a = __builtin_fmaf((DA), 2.f, s1a);                     \
    S3[0] = __builtin_fmaf(cf, (PLO).x, S3[0]);               \
    S3[1] = __builtin_fmaf(cf, (PLO).y, S3[1]);               \
    S3[2] = __builtin_fmaf(cf, (PLO).z, S3[2]);               \
    S3[3] = __builtin_fmaf(cf, (PLO).w, S3[3]);               \
    S3[4] = __builtin_fmaf(cf, rl((EX), 32 + (SI)), S3[4]);   \
    S3[5] = __builtin_fmaf(cf, rl((EX), 40 + (SI)), S3[5]);   \
    S3[6] = __builtin_fmaf(cf, rl((EX), 48 + (SI)), S3[6]);   \
    S3[7] = __builtin_fmaf(cf, rl((EX), 56 + (SI)), S3[7]);   \
  } while (0)

// one 4-step block consuming SET; E = e0t/e1t; SI = J&7 (compile-time)
#define CB(SET, E, SI)                                        \
  do {                                                        \
    STEP_H(SET##av.x, SET##bv.x, SET##p0, (E).x, SI);         \
    STEP_H(SET##av.y, SET##bv.y, SET##p1, (E).y, SI);         \
    STEP_H(SET##av.z, SET##bv.z, SET##p2, (E).z, SI);         \
    STEP_H(SET##av.w, SET##bv.w, SET##p3, (E).w, SI);         \
  } while (0)

__global__ __launch_bounds__(256, 3)
void sig_chunks_kernel(const float* __restrict__ path, float* __restrict__ csig,
                       int G, int CPC) {
  __shared__ __align__(16) float As[4][AWSZ];   // 4 KB
  __shared__ __align__(16) float Bs[4][BWSZ];   // 8.7 KB
  const int wid  = __builtin_amdgcn_readfirstlane((int)(threadIdx.x >> 6));
  const int lane = (int)(threadIdx.x & 63);
  const int ia = lane >> 3;   // 'a' == staging channel
  const int ib = lane & 7;    // 'b' == staging position
  const int wglob = __builtin_amdgcn_readfirstlane((int)blockIdx.x) * 4 + wid;
  const int samp = wglob / G;
  const int g    = wglob - samp * G;
  const int ts = g * CPC;
  const int te = (ts + CPC < NINC) ? (ts + CPC) : NINC;   // exclusive end
  const float* pbase = path + (size_t)samp * (C_ * L_);
  float* as_ = As[wid];
  float* bs  = Bs[wid];

  const int si = ib;
  const float* prow = pbase + ia * L_;
  const int grp = lane & ~7;
  const float* pa = bs + ia * BSTR;
  const float* pb = bs + ib * BSTR;

  // swizzled lo-channel A-write pointers (lanes with ia<4 store)
  const int rsw = (si >> 1) & 3;
  float* awb = as_ + (ia & 3);
  float* aw0 = awb + (si * 4 + (0 ^ rsw)) * 4;
  float* aw1 = awb + (si * 4 + (1 ^ rsw)) * 4;
  float* aw2 = awb + (si * 4 + (2 ^ rsw)) * 4;
  float* aw3 = awb + (si * 4 + (3 ^ rsw)) * 4;

  float S3[8];
#pragma unroll
  for (int k = 0; k < 8; ++k) S3[k] = 0.f;
  float S2 = 0.f, s1a = 0.f;

  const int ntiles = (CPC + TILE - 1) / TILE;   // uniform across grid

  // prologue: prefetch tile 0 + boundary
  float4 r0 = *(const float4*)(prow + ts + si * 4);
  float4 r1 = *(const float4*)(prow + ts + 32 + si * 4);
  float bnd = prow[ts + TILE];
  float4 e0t, e1t;   // this tile's halved diffs — live through compute

  float4 Ap0, Ap1, Ap2, Ap3, Aav, Abv;
  float4 Bp0, Bp1, Bp2, Bp3, Bav, Bbv;

  for (int tt = 0; tt < ntiles; ++tt) {
    const int t0 = ts + tt * TILE;
    const int cnt_ = te - t0;
    const int cnt = (cnt_ < TILE) ? cnt_ : TILE;

    // ---- stage tile tt: halved diffs -> e0t/e1t (kept), Bc, A-lo ----
    {
      const float4 v0 = r0, v1 = r1;
      const float sA = __shfl(v0.x, lane + 1);
      const float sB = __shfl(v1.x, grp);
      const float sC = __shfl(v1.x, lane + 1);
      const float n0 = (si == 7) ? sB : sA;
      const float n1 = (si == 7) ? bnd : sC;
      e0t.x = (v0.y - v0.x) * 0.5f;
      e0t.y = (v0.z - v0.y) * 0.5f;
      e0t.z = (v0.w - v0.z) * 0.5f;
      e0t.w = (n0 - v0.w) * 0.5f;
      e1t.x = (v1.y - v1.x) * 0.5f;
      e1t.y = (v1.z - v1.y) * 0.5f;
      e1t.z = (v1.w - v1.z) * 0.5f;
      e1t.w = (n1 - v1.w) * 0.5f;
      *(float4*)(bs + ia * BSTR + si * 4) = e0t;
      *(float4*)(bs + ia * BSTR + 32 + si * 4) = e1t;
      if (ia < 4) {   // lo-channel swizzled transpose writes
        aw0[0] = e0t.x;
        aw1[0] = e0t.y;
        aw2[0] = e0t.z;
        aw3[0] = e0t.w;
        aw0[128] = e1t.x;
        aw1[128] = e1t.y;
        aw2[128] = e1t.z;
        aw3[128] = e1t.w;
      }
    }

    // ---- prefetch tile tt+1 (r0/r1 free; e0t/e1t stay live) ----
    if (tt + 1 < ntiles) {
      const int t1g = t0 + TILE;
      r0 = *(const float4*)(prow + t1g + si * 4);
      r1 = *(const float4*)(prow + t1g + 32 + si * 4);
      const int bn = t1g + TILE;
      bnd = (bn < L_) ? prow[bn] : 0.f;
    }

    // ---- compute tile tt: 16 4-step blocks, A/B register double-buffer ----
    if (cnt == TILE) {
      LDP(A, 0);
#pragma unroll
      for (int jj = 0; jj < 8; ++jj) {
        LDP(B, 2 * jj + 1);
        CB(A, (2 * jj < 8 ? e0t : e1t), (2 * jj) & 7);
        if (jj < 7) { LDP(A, 2 * jj + 2); }
        CB(B, (2 * jj + 1 < 8 ? e0t : e1t), (2 * jj + 1) & 7);
      }
    } else {
      // tail tile (only the last chunk's last tile, cnt=63): cold path,
      // all 8 channels via uniform b32 reads from Bc.
      for (int u = 0; u < cnt; ++u) {
        const float dav = pa[u];
        const float dbv = pb[u];
        const float w_ = __builtin_fmaf(dav, (2.f / 3.f), s1a);
        const float z_ = __builtin_fmaf(dav, (4.f / 3.f), s1a);
        const float cf = __builtin_fmaf(dbv, w_, S2);
        S2  = __builtin_fmaf(dbv, z_, cf);
        s1a = __builtin_fmaf(dav, 2.f, s1a);
#pragma unroll
        for (int k = 0; k < 8; ++k)
          S3[k] = __builtin_fmaf(cf, bs[k * BSTR + u], S3[k]);
      }
    }
  }

  float* cs = csig + ((size_t)samp * G + g) * SIGDIM;
  if (ib == 0) cs[ia] = s1a;
  cs[8 + lane] = S2;
  float4 o0, o1;
  o0.x = 2.f * S3[0]; o0.y = 2.f * S3[1]; o0.z = 2.f * S3[2]; o0.w = 2.f * S3[3];
  o1.x = 2.f * S3[4]; o1.y = 2.f * S3[5]; o1.z = 2.f * S3[6]; o1.w = 2.f * S3[7];
  *(float4*)(cs + 72 + lane * 8)     = o0;
  *(float4*)(cs + 72 + lane * 8 + 4) = o1;
}

__global__ __launch_bounds__(256)
void sig_combine_kernel(const float* __restrict__ csig, float* __restrict__ out, int G) {
  const int wid  = __builtin_amdgcn_readfirstlane((int)(threadIdx.x >> 6));
  const int lane = (int)(threadIdx.x & 63);
  const int ia = lane >> 3, ib = lane & 7;
  const int samp = __builtin_amdgcn_readfirstlane((int)blockIdx.x) * 4 + wid;
  const float* base = csig + (size_t)samp * G * SIGDIM;

  float R1a = base[ia];
  float R2  = base[8 + lane];
  float R3[8];
#pragma unroll
  for (int k = 0; k < 8; ++k) R3[k] = base[72 + lane * 8 + k];

  for (int g = 1; g < G; ++g) {
    const float* T = base + g * SIGDIM;
    float sT1[8];
#pragma unroll
    for (int k = 0; k < 8; ++k) sT1[k] = T[k];
    const float T1a  = T[ia];
    const float T1b  = T[ib];
    const float T2ab = T[8 + lane];
    float T2b[8], T3v[8];
#pragma unroll
    for (int k = 0; k < 8; ++k) T2b[k] = T[8 + ib * 8 + k];
#pragma unroll
    for (int k = 0; k < 8; ++k) T3v[k] = T[72 + lane * 8 + k];
    const float R1o = R1a, R2o = R2;
#pragma unroll
    for (int k = 0; k < 8; ++k)
      R3[k] += T3v[k] + R1o * T2b[k] + R2o * sT1[k];
    R2  += T2ab + R1o * T1b;
    R1a += T1a;
  }

  float* o = out + (size_t)samp * SIGDIM;
  if (ib == 0) o[ia] = R1a;
  o[8 + lane] = R2;
#pragma unroll
  for (int k = 0; k < 8; ++k) o[72 + lane * 8 + k] = R3[k];
}

extern "C" void kernel_launch(void* const* d_in, const int* in_sizes, int n_in,
                              void* d_out, int out_size, void* d_ws, size_t ws_size,
                              hipStream_t stream) {
  (void)in_sizes; (void)n_in; (void)out_size;
  const float* path = (const float*)d_in[0];
  float* out = (float*)d_out;
  float* ws  = (float*)d_ws;

  int G = 16;
  while (G > 1 && (size_t)B_ * G * SIGDIM * sizeof(float) > ws_size) G >>= 1;
  const int CPC = (NINC + G - 1) / G;   // increments per chunk

  sig_chunks_kernel<<<dim3(B_ * G / 4), dim3(256), 0, stream>>>(path, ws, G, CPC);
  sig_combine_kernel<<<dim3(B_ / 4), dim3(256), 0, stream>>>(ws, out, G);
}